// Round 2
// baseline (1471.045 us; speedup 1.0000x reference)
//
#include <hip/hip_runtime.h>

#define N_NODES 50000
#define N_EDGES 800000
// feats: 512 -> 512 -> 512 -> 256; K is always 512. Internal dtype: fp16.
// H (GEMM output / agg input) is stored CHUNK-BLOCKED: [chunk][node][32feats],
// chunk = col>>5. 32 feats * 2B = 64B per node per chunk -> one chunk array is
// 50000*64B = 3.2MB < 4MiB per-XCD L2. Aggregation grid pins chunk->XCD via
// bid%8 round-robin (gridDim.x=8, z=phase), so the random gather becomes
// L2-resident instead of 8x51MB of compulsory fabric traffic.

typedef __attribute__((ext_vector_type(8))) _Float16 half8;
typedef __attribute__((ext_vector_type(4))) float f32x4;
typedef __attribute__((ext_vector_type(2))) float f32x2;
typedef __attribute__((ext_vector_type(8))) unsigned short ushort8;

// ---------------- fp16 helpers ----------------
static __device__ __forceinline__ unsigned short f2h(float f) {
    _Float16 h = (_Float16)f;   // RNE
    return __builtin_bit_cast(unsigned short, h);
}
static __device__ __forceinline__ float h2f(unsigned short u) {
    return (float)__builtin_bit_cast(_Float16, u);
}

// async global->LDS, 16B per lane (wave-uniform LDS base + lane*16 layout)
static __device__ __forceinline__ void async16(unsigned short* lds, const unsigned short* g) {
    __builtin_amdgcn_global_load_lds(
        (const __attribute__((address_space(1))) void*)g,
        (__attribute__((address_space(3))) void*)lds, 16, 0, 0);
}

// ---------------- int degree histograms ----------------
__global__ void hist_kernel(const int* __restrict__ src, const int* __restrict__ dst,
                            int* __restrict__ outc, int* __restrict__ inc) {
    int i = blockIdx.x * blockDim.x + threadIdx.x;
    if (i < N_EDGES) {
        atomicAdd(&outc[src[i]], 1);
        atomicAdd(&inc[dst[i]], 1);
    }
}

__global__ void norm_kernel(const int* __restrict__ outc, const int* __restrict__ inc,
                            float* __restrict__ outn, float* __restrict__ inn) {
    int i = blockIdx.x * blockDim.x + threadIdx.x;
    if (i < N_NODES) {
        outn[i] = rsqrtf(fmaxf((float)outc[i], 1.0f));
        inn[i]  = rsqrtf(fmaxf((float)inc[i], 1.0f));
    }
}

// ---------------- hierarchical exclusive scan (3 kernels) ----------------
__global__ __launch_bounds__(256) void scan1(const int* __restrict__ cnt,
                                             int* __restrict__ row_start,
                                             int* __restrict__ bsum, int n) {
    __shared__ int t[256];
    int tid = threadIdx.x;
    int i = blockIdx.x * 256 + tid;
    int v = (i < n) ? cnt[i] : 0;
    t[tid] = v;
    __syncthreads();
#pragma unroll
    for (int off = 1; off < 256; off <<= 1) {
        int x = (tid >= off) ? t[tid - off] : 0;
        __syncthreads();
        t[tid] += x;
        __syncthreads();
    }
    if (i < n) row_start[i] = t[tid] - v;
    if (tid == 255) bsum[blockIdx.x] = t[255];
}

__global__ __launch_bounds__(256) void scan2(int* __restrict__ bsum,
                                             int* __restrict__ boff,
                                             int* __restrict__ row_start, int nb) {
    __shared__ int t[256];
    int tid = threadIdx.x;
    int v = (tid < nb) ? bsum[tid] : 0;
    t[tid] = v;
    __syncthreads();
#pragma unroll
    for (int off = 1; off < 256; off <<= 1) {
        int x = (tid >= off) ? t[tid - off] : 0;
        __syncthreads();
        t[tid] += x;
        __syncthreads();
    }
    if (tid < nb) boff[tid] = t[tid] - v;
    if (tid == 0) row_start[N_NODES] = N_EDGES;
}

__global__ __launch_bounds__(256) void scan3(int* __restrict__ row_start,
                                             const int* __restrict__ boff, int n) {
    int i = blockIdx.x * 256 + threadIdx.x;
    if (i < n) row_start[i] += boff[blockIdx.x];
}

// ---------------- CSR fill ----------------
__global__ void fill_kernel(const int* __restrict__ src, const int* __restrict__ dst,
                            const int* __restrict__ row_start, int* __restrict__ cursor,
                            int* __restrict__ csr_src) {
    int e = blockIdx.x * blockDim.x + threadIdx.x;
    if (e < N_EDGES) {
        int d = dst[e];
        int pos = atomicAdd(&cursor[d], 1);
        csr_src[row_start[d] + pos] = src[e];
    }
}

// ---------------- W [K,N] fp32 -> Wt [N,K] fp16 (transpose) ----------------
__global__ __launch_bounds__(256) void conv_W(const float* __restrict__ W,
                                              unsigned short* __restrict__ Wt,
                                              int K, int N) {
    __shared__ float t[32][33];
    int tx = threadIdx.x & 31, ty = threadIdx.x >> 5;   // 32 x 8
    int kb = blockIdx.x * 32, nb = blockIdx.y * 32;
#pragma unroll
    for (int i = 0; i < 4; ++i)
        t[ty + 8 * i][tx] = W[(size_t)(kb + ty + 8 * i) * N + nb + tx];
    __syncthreads();
#pragma unroll
    for (int i = 0; i < 4; ++i) {
        float v = t[tx][ty + 8 * i];
        int n = nb + ty + 8 * i, k = kb + tx;
        Wt[(size_t)n * K + k] = f2h(v);
    }
}

// ---------------- feat [M,512] fp32 -> (outn[row]*feat) fp16 ----------------
__global__ void conv_A(const float4* __restrict__ feat4, const float* __restrict__ outn,
                       ushort4* __restrict__ Af, long total4) {
    long i = (long)blockIdx.x * blockDim.x + threadIdx.x;
    if (i >= total4) return;
    int row = (int)(i >> 7);            // 512/4 = 128 float4 per row
    float s = outn[row];
    float4 v = feat4[i];
    ushort4 h;
    h.x = f2h(v.x * s);
    h.y = f2h(v.y * s);
    h.z = f2h(v.z * s);
    h.w = f2h(v.w * s);
    Af[i] = h;
}

// ---------------- MFMA GEMM: C = A @ B^T, fp16 in/out, fp32 acc, K=512 ----------------
// 128x128 tile, BK=32, 256 threads = 4 waves; global_load_lds (16B) staging.
// Output C is written in CHUNK-BLOCKED layout: C[((col>>5)*M + row)*32 + (col&31)].
__global__ __launch_bounds__(256) void gemm_mfma(
    const unsigned short* __restrict__ A, const unsigned short* __restrict__ B,
    unsigned short* __restrict__ C, int M, int N)
{
    const int K = 512;
    __shared__ unsigned short sA[128 * 32];
    __shared__ unsigned short sB[128 * 32];

    const int tid = threadIdx.x;
    const int rowBase = blockIdx.x * 128;
    const int colBase = blockIdx.y * 128;
    const int wave = tid >> 6;
    const int lane = tid & 63;
    const int wr = (wave >> 1) * 64;
    const int wc = (wave & 1) * 64;
    const int lrow = lane & 15;
    const int quad = lane >> 4;

    f32x4 acc[4][4] = {};

    // staging: thread tid -> row tid>>2 (and +64), k-chunk (tid&3)*8; LDS dest = tid*16 B
    const int crow = tid >> 2;
    const int ck   = (tid & 3) * 8;
    const int ar0 = min(rowBase + crow, M - 1);
    const int ar1 = min(rowBase + 64 + crow, M - 1);
    const int bn0 = colBase + crow;
    const int bn1 = colBase + 64 + crow;
    const int ldsOf0 = tid * 8;          // ushort units
    const int ldsOf1 = 64 * 32 + tid * 8;

    for (int k0 = 0; k0 < K; k0 += 32) {
        __syncthreads();   // previous tile's compute done before overwrite
        async16(sA + ldsOf0, A + (size_t)ar0 * K + k0 + ck);
        async16(sA + ldsOf1, A + (size_t)ar1 * K + k0 + ck);
        async16(sB + ldsOf0, B + (size_t)bn0 * K + k0 + ck);
        async16(sB + ldsOf1, B + (size_t)bn1 * K + k0 + ck);
        __syncthreads();   // drains vmcnt (global_load_lds) + barrier

        half8 av[4], bv[4];
#pragma unroll
        for (int mt = 0; mt < 4; ++mt)
            av[mt] = *(const half8*)&sA[(wr + mt * 16 + lrow) * 32 + quad * 8];
#pragma unroll
        for (int nt = 0; nt < 4; ++nt)
            bv[nt] = *(const half8*)&sB[(wc + nt * 16 + lrow) * 32 + quad * 8];
#pragma unroll
        for (int mt = 0; mt < 4; ++mt)
#pragma unroll
            for (int nt = 0; nt < 4; ++nt)
                acc[mt][nt] = __builtin_amdgcn_mfma_f32_16x16x32_f16(av[mt], bv[nt], acc[mt][nt], 0, 0, 0);
    }

    // epilogue: C/D layout col=lane&15, row=quad*4+reg; store fp16, chunk-blocked.
#pragma unroll
    for (int mt = 0; mt < 4; ++mt) {
        int grow0 = rowBase + wr + mt * 16 + quad * 4;
#pragma unroll
        for (int nt = 0; nt < 4; ++nt) {
            int gcol = colBase + wc + nt * 16 + lrow;
            size_t chunkBase = (size_t)(gcol >> 5) * M * 32 + (gcol & 31);
#pragma unroll
            for (int r = 0; r < 4; ++r) {
                int grow = grow0 + r;
                if (grow < M) C[chunkBase + (size_t)grow * 32] = f2h(acc[mt][nt][r]);
            }
        }
    }
}

// ---------------- chunked gather-aggregate: H chunked [nc][N][32] fp16 ----------------
// grid: (8, 3125, phases). chunk = z*8 + x -> XCD = bid%8 = x (one resident 3.2MB
// chunk per XCD per phase). Block = 4 waves x 4 nodes. Wave: 16-lane group g
// handles edge slot g; lane f owns feat pair (2f,2f+1) of the chunk.
// Mid layers: out = relu(acc*inn + b) * outn -> fp16 into linear Af[node][512].
__global__ __launch_bounds__(256) void agg_f16_chunked(
    const unsigned short* __restrict__ H, const int* __restrict__ csr_src,
    const int* __restrict__ row_start, const float* __restrict__ inn,
    const float* __restrict__ outn, const float* __restrict__ bias,
    unsigned short* __restrict__ Af)
{
    const int wave = threadIdx.x >> 6;
    const int lane = threadIdx.x & 63;
    const int g = lane >> 4;           // edge slot 0..3
    const int f = lane & 15;           // feat-pair index 0..15
    const int c = blockIdx.z * 8 + blockIdx.x;         // chunk id
    const int baseNode = blockIdx.y * 16 + wave * 4;

    const unsigned short* Hc = H + (size_t)c * N_NODES * 32 + 2 * f;
    const float2 bf = ((const float2*)(bias + c * 32))[f];

    for (int nn = 0; nn < 4; ++nn) {
        int d = baseNode + nn;
        if (d >= N_NODES) return;      // uniform per wave
        int start = row_start[d];
        int end   = row_start[d + 1];
        float a0 = 0.f, a1 = 0.f;
        for (int j = start; j < end; j += 8) {
            int e0 = j + g, e1 = j + 4 + g;
            if (e0 < end) {
                int i0 = __builtin_nontemporal_load(csr_src + e0);
                unsigned int u = *(const unsigned int*)(Hc + (size_t)i0 * 32);
                a0 += h2f((unsigned short)(u & 0xffffu));
                a1 += h2f((unsigned short)(u >> 16));
            }
            if (e1 < end) {
                int i1 = __builtin_nontemporal_load(csr_src + e1);
                unsigned int u = *(const unsigned int*)(Hc + (size_t)i1 * 32);
                a0 += h2f((unsigned short)(u & 0xffffu));
                a1 += h2f((unsigned short)(u >> 16));
            }
        }
        // reduce over the 4 edge slots (lanes xor 16, xor 32)
        a0 += __shfl_xor(a0, 16); a0 += __shfl_xor(a0, 32);
        a1 += __shfl_xor(a1, 16); a1 += __shfl_xor(a1, 32);
        if (g == 0) {
            float s = inn[d], so = outn[d];
            unsigned int h0 = f2h(fmaxf(a0 * s + bf.x, 0.f) * so);
            unsigned int h1 = f2h(fmaxf(a1 * s + bf.y, 0.f) * so);
            unsigned int pk = h0 | (h1 << 16);
            __builtin_nontemporal_store(pk,
                (unsigned int*)(Af + (size_t)d * 512 + c * 32) + f);
        }
    }
}

// ---------------- final chunked aggregate: H chunked [8][N][32] -> fp32 out ----------------
__global__ __launch_bounds__(256) void agg_f32_chunked(
    const unsigned short* __restrict__ H, const int* __restrict__ csr_src,
    const int* __restrict__ row_start, const float* __restrict__ inn,
    const float* __restrict__ bias, float* __restrict__ out)
{
    const int wave = threadIdx.x >> 6;
    const int lane = threadIdx.x & 63;
    const int g = lane >> 4;
    const int f = lane & 15;
    const int c = blockIdx.x;                          // chunk id 0..7
    const int baseNode = blockIdx.y * 16 + wave * 4;

    const unsigned short* Hc = H + (size_t)c * N_NODES * 32 + 2 * f;
    const float2 bf = ((const float2*)(bias + c * 32))[f];

    for (int nn = 0; nn < 4; ++nn) {
        int d = baseNode + nn;
        if (d >= N_NODES) return;
        int start = row_start[d];
        int end   = row_start[d + 1];
        float a0 = 0.f, a1 = 0.f;
        for (int j = start; j < end; j += 8) {
            int e0 = j + g, e1 = j + 4 + g;
            if (e0 < end) {
                int i0 = __builtin_nontemporal_load(csr_src + e0);
                unsigned int u = *(const unsigned int*)(Hc + (size_t)i0 * 32);
                a0 += h2f((unsigned short)(u & 0xffffu));
                a1 += h2f((unsigned short)(u >> 16));
            }
            if (e1 < end) {
                int i1 = __builtin_nontemporal_load(csr_src + e1);
                unsigned int u = *(const unsigned int*)(Hc + (size_t)i1 * 32);
                a0 += h2f((unsigned short)(u & 0xffffu));
                a1 += h2f((unsigned short)(u >> 16));
            }
        }
        a0 += __shfl_xor(a0, 16); a0 += __shfl_xor(a0, 32);
        a1 += __shfl_xor(a1, 16); a1 += __shfl_xor(a1, 32);
        if (g == 0) {
            float s = inn[d];
            f32x2 r;
            r.x = a0 * s + bf.x;
            r.y = a1 * s + bf.y;
            __builtin_nontemporal_store(r,
                (f32x2*)(out + (size_t)d * 256 + c * 32) + f);
        }
    }
}

extern "C" void kernel_launch(void* const* d_in, const int* in_sizes, int n_in,
                              void* d_out, int out_size, void* d_ws, size_t ws_size,
                              hipStream_t stream) {
    const float* feat = (const float*)d_in[0];
    const int*   src  = (const int*)d_in[1];
    const int*   dst  = (const int*)d_in[2];
    const float* W0   = (const float*)d_in[3];
    const float* b0   = (const float*)d_in[4];
    const float* W1   = (const float*)d_in[5];
    const float* b1   = (const float*)d_in[6];
    const float* W2   = (const float*)d_in[7];
    const float* b2   = (const float*)d_in[8];
    float* out = (float*)d_out;

    // ---- workspace bump allocator (64B aligned) ----
    char* p = (char*)d_ws;
    auto alloc = [&](size_t bytes) {
        char* r = p;
        p += (bytes + 63) & ~(size_t)63;
        return r;
    };
    float* outn = (float*)alloc(N_NODES * 4);
    float* inn  = (float*)alloc(N_NODES * 4);
    int* outc      = (int*)alloc(N_NODES * 4);
    int* inc       = (int*)alloc(N_NODES * 4);
    int* cursor    = (int*)alloc(N_NODES * 4);
    int* row_start = (int*)alloc((N_NODES + 1) * 4);
    int* bsum      = (int*)alloc(256 * 4);
    int* boff      = (int*)alloc(256 * 4);
    int* csr_src   = (int*)alloc(N_EDGES * 4);
    unsigned short* W0t = (unsigned short*)alloc(512 * 512 * 2);
    unsigned short* W1t = (unsigned short*)alloc(512 * 512 * 2);
    unsigned short* W2t = (unsigned short*)alloc(256 * 512 * 2);
    unsigned short* Af  = (unsigned short*)alloc((size_t)N_NODES * 512 * 2);
    unsigned short* H   = (unsigned short*)alloc((size_t)N_NODES * 512 * 2);

    const int NB = (N_NODES + 255) / 256;   // 196

    // ---- degrees + norms + CSR ----
    hipMemsetAsync(outc, 0, 3 * N_NODES * sizeof(int), stream);  // outc, inc, cursor contiguous
    hist_kernel<<<(N_EDGES + 255) / 256, 256, 0, stream>>>(src, dst, outc, inc);
    norm_kernel<<<(N_NODES + 255) / 256, 256, 0, stream>>>(outc, inc, outn, inn);
    scan1<<<NB, 256, 0, stream>>>(inc, row_start, bsum, N_NODES);
    scan2<<<1, 256, 0, stream>>>(bsum, boff, row_start, NB);
    scan3<<<NB, 256, 0, stream>>>(row_start, boff, N_NODES);
    fill_kernel<<<(N_EDGES + 255) / 256, 256, 0, stream>>>(src, dst, row_start, cursor, csr_src);

    // ---- weight transpose to fp16 ----
    conv_W<<<dim3(16, 16), 256, 0, stream>>>(W0, W0t, 512, 512);
    conv_W<<<dim3(16, 16), 256, 0, stream>>>(W1, W1t, 512, 512);
    conv_W<<<dim3(16, 8),  256, 0, stream>>>(W2, W2t, 512, 256);

    // ---- feature scale to fp16 ----
    long total4 = (long)N_NODES * 128;
    conv_A<<<(int)((total4 + 255) / 256), 256, 0, stream>>>(
        (const float4*)feat, outn, (ushort4*)Af, total4);

    dim3 g512((N_NODES + 127) / 128, 4);
    dim3 g256((N_NODES + 127) / 128, 2);
    const int NT = (N_NODES + 15) / 16;     // 3125 node tiles (16 nodes/block)
    dim3 gAgg512(8, NT, 2);                 // 16 chunks: xcd = chunk%8, 2 phases
    dim3 gAgg256(8, NT, 1);                 // 8 chunks: one per XCD

    // ---- layer 0 ----
    gemm_mfma<<<g512, 256, 0, stream>>>(Af, W0t, H, N_NODES, 512);
    agg_f16_chunked<<<gAgg512, 256, 0, stream>>>(
        H, csr_src, row_start, inn, outn, b0, Af);

    // ---- layer 1 ----
    gemm_mfma<<<g512, 256, 0, stream>>>(Af, W1t, H, N_NODES, 512);
    agg_f16_chunked<<<gAgg512, 256, 0, stream>>>(
        H, csr_src, row_start, inn, outn, b1, Af);

    // ---- layer 2 (256 out, no relu, fp32) ----
    gemm_mfma<<<g256, 256, 0, stream>>>(Af, W2t, H, N_NODES, 256);
    agg_f32_chunked<<<gAgg256, 256, 0, stream>>>(
        H, csr_src, row_start, inn, b2, out);
}

// Round 3
// 887.026 us; speedup vs baseline: 1.6584x; 1.6584x over previous
//
#include <hip/hip_runtime.h>

#define N_NODES 50000
#define N_EDGES 800000
// feats: 512 -> 512 -> 512 -> 256; K is always 512. Internal dtype: fp16.
// H (GEMM output / agg input) is stored CHUNK-BLOCKED: [chunk][node][32feats],
// chunk = col>>5. One chunk = 50000*64B = 3.2MB < 4MiB per-XCD L2. Aggregation
// grid pins chunk->XCD via bid%8 (gridDim.x=8), so random gathers are L2-hits.
// v2 agg: LDS-staged edge indices (decouple idx->gather latency chain) +
// 8 edges x 8 lanes x 8B gathers (512B/instr, x2 unroll) + butterfly reduce.

typedef __attribute__((ext_vector_type(8))) _Float16 half8;
typedef __attribute__((ext_vector_type(4))) float f32x4;
typedef __attribute__((ext_vector_type(2))) float f32x2;
typedef __attribute__((ext_vector_type(2))) unsigned int u32x2;
typedef __attribute__((ext_vector_type(8))) unsigned short ushort8;

// ---------------- fp16 helpers ----------------
static __device__ __forceinline__ unsigned short f2h(float f) {
    _Float16 h = (_Float16)f;   // RNE
    return __builtin_bit_cast(unsigned short, h);
}
static __device__ __forceinline__ float h2f(unsigned short u) {
    return (float)__builtin_bit_cast(_Float16, u);
}

// async global->LDS, 16B per lane (wave-uniform LDS base + lane*16 layout)
static __device__ __forceinline__ void async16(unsigned short* lds, const unsigned short* g) {
    __builtin_amdgcn_global_load_lds(
        (const __attribute__((address_space(1))) void*)g,
        (__attribute__((address_space(3))) void*)lds, 16, 0, 0);
}

// ---------------- int degree histograms ----------------
__global__ void hist_kernel(const int* __restrict__ src, const int* __restrict__ dst,
                            int* __restrict__ outc, int* __restrict__ inc) {
    int i = blockIdx.x * blockDim.x + threadIdx.x;
    if (i < N_EDGES) {
        atomicAdd(&outc[src[i]], 1);
        atomicAdd(&inc[dst[i]], 1);
    }
}

__global__ void norm_kernel(const int* __restrict__ outc, const int* __restrict__ inc,
                            float* __restrict__ outn, float* __restrict__ inn) {
    int i = blockIdx.x * blockDim.x + threadIdx.x;
    if (i < N_NODES) {
        outn[i] = rsqrtf(fmaxf((float)outc[i], 1.0f));
        inn[i]  = rsqrtf(fmaxf((float)inc[i], 1.0f));
    }
}

// ---------------- hierarchical exclusive scan (3 kernels) ----------------
__global__ __launch_bounds__(256) void scan1(const int* __restrict__ cnt,
                                             int* __restrict__ row_start,
                                             int* __restrict__ bsum, int n) {
    __shared__ int t[256];
    int tid = threadIdx.x;
    int i = blockIdx.x * 256 + tid;
    int v = (i < n) ? cnt[i] : 0;
    t[tid] = v;
    __syncthreads();
#pragma unroll
    for (int off = 1; off < 256; off <<= 1) {
        int x = (tid >= off) ? t[tid - off] : 0;
        __syncthreads();
        t[tid] += x;
        __syncthreads();
    }
    if (i < n) row_start[i] = t[tid] - v;
    if (tid == 255) bsum[blockIdx.x] = t[255];
}

__global__ __launch_bounds__(256) void scan2(int* __restrict__ bsum,
                                             int* __restrict__ boff,
                                             int* __restrict__ row_start, int nb) {
    __shared__ int t[256];
    int tid = threadIdx.x;
    int v = (tid < nb) ? bsum[tid] : 0;
    t[tid] = v;
    __syncthreads();
#pragma unroll
    for (int off = 1; off < 256; off <<= 1) {
        int x = (tid >= off) ? t[tid - off] : 0;
        __syncthreads();
        t[tid] += x;
        __syncthreads();
    }
    if (tid < nb) boff[tid] = t[tid] - v;
    if (tid == 0) row_start[N_NODES] = N_EDGES;
}

__global__ __launch_bounds__(256) void scan3(int* __restrict__ row_start,
                                             const int* __restrict__ boff, int n) {
    int i = blockIdx.x * 256 + threadIdx.x;
    if (i < n) row_start[i] += boff[blockIdx.x];
}

// ---------------- CSR fill ----------------
__global__ void fill_kernel(const int* __restrict__ src, const int* __restrict__ dst,
                            const int* __restrict__ row_start, int* __restrict__ cursor,
                            int* __restrict__ csr_src) {
    int e = blockIdx.x * blockDim.x + threadIdx.x;
    if (e < N_EDGES) {
        int d = dst[e];
        int pos = atomicAdd(&cursor[d], 1);
        csr_src[row_start[d] + pos] = src[e];
    }
}

// ---------------- W [K,N] fp32 -> Wt [N,K] fp16 (transpose) ----------------
__global__ __launch_bounds__(256) void conv_W(const float* __restrict__ W,
                                              unsigned short* __restrict__ Wt,
                                              int K, int N) {
    __shared__ float t[32][33];
    int tx = threadIdx.x & 31, ty = threadIdx.x >> 5;   // 32 x 8
    int kb = blockIdx.x * 32, nb = blockIdx.y * 32;
#pragma unroll
    for (int i = 0; i < 4; ++i)
        t[ty + 8 * i][tx] = W[(size_t)(kb + ty + 8 * i) * N + nb + tx];
    __syncthreads();
#pragma unroll
    for (int i = 0; i < 4; ++i) {
        float v = t[tx][ty + 8 * i];
        int n = nb + ty + 8 * i, k = kb + tx;
        Wt[(size_t)n * K + k] = f2h(v);
    }
}

// ---------------- feat [M,512] fp32 -> (outn[row]*feat) fp16 ----------------
__global__ void conv_A(const float4* __restrict__ feat4, const float* __restrict__ outn,
                       ushort4* __restrict__ Af, long total4) {
    long i = (long)blockIdx.x * blockDim.x + threadIdx.x;
    if (i >= total4) return;
    int row = (int)(i >> 7);            // 512/4 = 128 float4 per row
    float s = outn[row];
    float4 v = feat4[i];
    ushort4 h;
    h.x = f2h(v.x * s);
    h.y = f2h(v.y * s);
    h.z = f2h(v.z * s);
    h.w = f2h(v.w * s);
    Af[i] = h;
}

// ---------------- MFMA GEMM: C = A @ B^T, fp16 in/out, fp32 acc, K=512 ----------------
// 128x128 tile, BK=32, 256 threads = 4 waves; global_load_lds (16B) staging.
// Output C is written in CHUNK-BLOCKED layout: C[((col>>5)*M + row)*32 + (col&31)].
__global__ __launch_bounds__(256) void gemm_mfma(
    const unsigned short* __restrict__ A, const unsigned short* __restrict__ B,
    unsigned short* __restrict__ C, int M, int N)
{
    const int K = 512;
    __shared__ unsigned short sA[128 * 32];
    __shared__ unsigned short sB[128 * 32];

    const int tid = threadIdx.x;
    const int rowBase = blockIdx.x * 128;
    const int colBase = blockIdx.y * 128;
    const int wave = tid >> 6;
    const int lane = tid & 63;
    const int wr = (wave >> 1) * 64;
    const int wc = (wave & 1) * 64;
    const int lrow = lane & 15;
    const int quad = lane >> 4;

    f32x4 acc[4][4] = {};

    // staging: thread tid -> row tid>>2 (and +64), k-chunk (tid&3)*8; LDS dest = tid*16 B
    const int crow = tid >> 2;
    const int ck   = (tid & 3) * 8;
    const int ar0 = min(rowBase + crow, M - 1);
    const int ar1 = min(rowBase + 64 + crow, M - 1);
    const int bn0 = colBase + crow;
    const int bn1 = colBase + 64 + crow;
    const int ldsOf0 = tid * 8;          // ushort units
    const int ldsOf1 = 64 * 32 + tid * 8;

    for (int k0 = 0; k0 < K; k0 += 32) {
        __syncthreads();   // previous tile's compute done before overwrite
        async16(sA + ldsOf0, A + (size_t)ar0 * K + k0 + ck);
        async16(sA + ldsOf1, A + (size_t)ar1 * K + k0 + ck);
        async16(sB + ldsOf0, B + (size_t)bn0 * K + k0 + ck);
        async16(sB + ldsOf1, B + (size_t)bn1 * K + k0 + ck);
        __syncthreads();   // drains vmcnt (global_load_lds) + barrier

        half8 av[4], bv[4];
#pragma unroll
        for (int mt = 0; mt < 4; ++mt)
            av[mt] = *(const half8*)&sA[(wr + mt * 16 + lrow) * 32 + quad * 8];
#pragma unroll
        for (int nt = 0; nt < 4; ++nt)
            bv[nt] = *(const half8*)&sB[(wc + nt * 16 + lrow) * 32 + quad * 8];
#pragma unroll
        for (int mt = 0; mt < 4; ++mt)
#pragma unroll
            for (int nt = 0; nt < 4; ++nt)
                acc[mt][nt] = __builtin_amdgcn_mfma_f32_16x16x32_f16(av[mt], bv[nt], acc[mt][nt], 0, 0, 0);
    }

    // epilogue: C/D layout col=lane&15, row=quad*4+reg; store fp16, chunk-blocked.
#pragma unroll
    for (int mt = 0; mt < 4; ++mt) {
        int grow0 = rowBase + wr + mt * 16 + quad * 4;
#pragma unroll
        for (int nt = 0; nt < 4; ++nt) {
            int gcol = colBase + wc + nt * 16 + lrow;
            size_t chunkBase = (size_t)(gcol >> 5) * M * 32 + (gcol & 31);
#pragma unroll
            for (int r = 0; r < 4; ++r) {
                int grow = grow0 + r;
                if (grow < M) C[chunkBase + (size_t)grow * 32] = f2h(acc[mt][nt][r]);
            }
        }
    }
}

// ---------------- chunked gather-aggregate v2 ----------------
// grid (8, 3125, phases). chunk c = z*8+x -> XCD x. Block: 256 thr = 4 waves,
// TILE=16 dst nodes (wave w -> nodes 4w..4w+3). Tile's edge indices staged to
// LDS cooperatively (nt, coalesced), then: 8 edge slots x 8 lanes x 8B gather
// (512B per wave instr, x2 unroll = 16 edges in flight); fp32 acc[node][4];
// butterfly (xor 8,16,32) over slots; lanes of slot 0 write 8B each.
#define AGG_TILE 16
#define AGG_MAXE 4096

__global__ __launch_bounds__(256) void agg_f16_chunked(
    const unsigned short* __restrict__ H, const int* __restrict__ csr_src,
    const int* __restrict__ row_start, const float* __restrict__ inn,
    const float* __restrict__ outn, const float* __restrict__ bias,
    unsigned short* __restrict__ Af)
{
    __shared__ int sIdx[AGG_MAXE];
    const int tid  = threadIdx.x;
    const int lane = tid & 63;
    const int wave = tid >> 6;
    const int slot = lane >> 3;          // edge slot 0..7
    const int f    = lane & 7;           // feat-quad 0..7 (8B of the 64B row)
    const int c = blockIdx.z * 8 + blockIdx.x;
    const int tileBase = blockIdx.y * AGG_TILE;

    const unsigned short* Hc = H + (size_t)c * (N_NODES * 32) + f * 4;

    int st[4], en[4];
#pragma unroll
    for (int nn = 0; nn < 4; ++nn) {
        int d = tileBase + wave * 4 + nn;          // 3125*16 == 50000: always valid
        st[nn] = row_start[d];
        en[nn] = row_start[d + 1];
    }
    const int eStart = row_start[tileBase];
    const int eEnd   = row_start[tileBase + AGG_TILE];

    float acc[4][4] = {};

    for (int b = eStart; b < eEnd; b += AGG_MAXE) {   // single batch in practice
        const int bEnd = min(b + AGG_MAXE, eEnd);
        __syncthreads();
        for (int e = b + tid; e < bEnd; e += 256)
            sIdx[e - b] = __builtin_nontemporal_load(csr_src + e);
        __syncthreads();

#pragma unroll
        for (int nn = 0; nn < 4; ++nn) {
            const int js = max(st[nn], b);
            const int je = min(en[nn], bEnd);
            int j = js;
            for (; j + 16 <= je; j += 16) {
                int i0 = sIdx[j - b + slot];
                int i1 = sIdx[j - b + 8 + slot];
                ushort4 u0 = *(const ushort4*)(Hc + (size_t)i0 * 32);
                ushort4 u1 = *(const ushort4*)(Hc + (size_t)i1 * 32);
                acc[nn][0] += h2f(u0.x) + h2f(u1.x);
                acc[nn][1] += h2f(u0.y) + h2f(u1.y);
                acc[nn][2] += h2f(u0.z) + h2f(u1.z);
                acc[nn][3] += h2f(u0.w) + h2f(u1.w);
            }
            for (; j < je; j += 8) {
                if (j + slot < je) {
                    int i0 = sIdx[j - b + slot];
                    ushort4 u0 = *(const ushort4*)(Hc + (size_t)i0 * 32);
                    acc[nn][0] += h2f(u0.x);
                    acc[nn][1] += h2f(u0.y);
                    acc[nn][2] += h2f(u0.z);
                    acc[nn][3] += h2f(u0.w);
                }
            }
        }
    }

#pragma unroll
    for (int nn = 0; nn < 4; ++nn) {
        float a0 = acc[nn][0], a1 = acc[nn][1];
        float a2 = acc[nn][2], a3 = acc[nn][3];
#pragma unroll
        for (int m = 8; m <= 32; m <<= 1) {
            a0 += __shfl_xor(a0, m);
            a1 += __shfl_xor(a1, m);
            a2 += __shfl_xor(a2, m);
            a3 += __shfl_xor(a3, m);
        }
        if (slot == 0) {
            int d = tileBase + wave * 4 + nn;
            float s = inn[d], so = outn[d];
            float4 bq = *(const float4*)(bias + c * 32 + f * 4);
            unsigned int h0 = f2h(fmaxf(a0 * s + bq.x, 0.f) * so);
            unsigned int h1 = f2h(fmaxf(a1 * s + bq.y, 0.f) * so);
            unsigned int h2 = f2h(fmaxf(a2 * s + bq.z, 0.f) * so);
            unsigned int h3 = f2h(fmaxf(a3 * s + bq.w, 0.f) * so);
            u32x2 pk;
            pk.x = h0 | (h1 << 16);
            pk.y = h2 | (h3 << 16);
            __builtin_nontemporal_store(pk,
                (u32x2*)(Af + (size_t)d * 512 + c * 32 + f * 4));
        }
    }
}

// ---------------- final chunked aggregate v2: fp32 out, no relu ----------------
__global__ __launch_bounds__(256) void agg_f32_chunked(
    const unsigned short* __restrict__ H, const int* __restrict__ csr_src,
    const int* __restrict__ row_start, const float* __restrict__ inn,
    const float* __restrict__ bias, float* __restrict__ out)
{
    __shared__ int sIdx[AGG_MAXE];
    const int tid  = threadIdx.x;
    const int lane = tid & 63;
    const int wave = tid >> 6;
    const int slot = lane >> 3;
    const int f    = lane & 7;
    const int c = blockIdx.x;                      // chunk 0..7
    const int tileBase = blockIdx.y * AGG_TILE;

    const unsigned short* Hc = H + (size_t)c * (N_NODES * 32) + f * 4;

    int st[4], en[4];
#pragma unroll
    for (int nn = 0; nn < 4; ++nn) {
        int d = tileBase + wave * 4 + nn;
        st[nn] = row_start[d];
        en[nn] = row_start[d + 1];
    }
    const int eStart = row_start[tileBase];
    const int eEnd   = row_start[tileBase + AGG_TILE];

    float acc[4][4] = {};

    for (int b = eStart; b < eEnd; b += AGG_MAXE) {
        const int bEnd = min(b + AGG_MAXE, eEnd);
        __syncthreads();
        for (int e = b + tid; e < bEnd; e += 256)
            sIdx[e - b] = __builtin_nontemporal_load(csr_src + e);
        __syncthreads();

#pragma unroll
        for (int nn = 0; nn < 4; ++nn) {
            const int js = max(st[nn], b);
            const int je = min(en[nn], bEnd);
            int j = js;
            for (; j + 16 <= je; j += 16) {
                int i0 = sIdx[j - b + slot];
                int i1 = sIdx[j - b + 8 + slot];
                ushort4 u0 = *(const ushort4*)(Hc + (size_t)i0 * 32);
                ushort4 u1 = *(const ushort4*)(Hc + (size_t)i1 * 32);
                acc[nn][0] += h2f(u0.x) + h2f(u1.x);
                acc[nn][1] += h2f(u0.y) + h2f(u1.y);
                acc[nn][2] += h2f(u0.z) + h2f(u1.z);
                acc[nn][3] += h2f(u0.w) + h2f(u1.w);
            }
            for (; j < je; j += 8) {
                if (j + slot < je) {
                    int i0 = sIdx[j - b + slot];
                    ushort4 u0 = *(const ushort4*)(Hc + (size_t)i0 * 32);
                    acc[nn][0] += h2f(u0.x);
                    acc[nn][1] += h2f(u0.y);
                    acc[nn][2] += h2f(u0.z);
                    acc[nn][3] += h2f(u0.w);
                }
            }
        }
    }

#pragma unroll
    for (int nn = 0; nn < 4; ++nn) {
        float a0 = acc[nn][0], a1 = acc[nn][1];
        float a2 = acc[nn][2], a3 = acc[nn][3];
#pragma unroll
        for (int m = 8; m <= 32; m <<= 1) {
            a0 += __shfl_xor(a0, m);
            a1 += __shfl_xor(a1, m);
            a2 += __shfl_xor(a2, m);
            a3 += __shfl_xor(a3, m);
        }
        if (slot == 0) {
            int d = tileBase + wave * 4 + nn;
            float s = inn[d];
            float4 bq = *(const float4*)(bias + c * 32 + f * 4);
            f32x4 r;
            r.x = a0 * s + bq.x;
            r.y = a1 * s + bq.y;
            r.z = a2 * s + bq.z;
            r.w = a3 * s + bq.w;
            __builtin_nontemporal_store(r,
                (f32x4*)(out + (size_t)d * 256 + c * 32 + f * 4));
        }
    }
}

extern "C" void kernel_launch(void* const* d_in, const int* in_sizes, int n_in,
                              void* d_out, int out_size, void* d_ws, size_t ws_size,
                              hipStream_t stream) {
    const float* feat = (const float*)d_in[0];
    const int*   src  = (const int*)d_in[1];
    const int*   dst  = (const int*)d_in[2];
    const float* W0   = (const float*)d_in[3];
    const float* b0   = (const float*)d_in[4];
    const float* W1   = (const float*)d_in[5];
    const float* b1   = (const float*)d_in[6];
    const float* W2   = (const float*)d_in[7];
    const float* b2   = (const float*)d_in[8];
    float* out = (float*)d_out;

    // ---- workspace bump allocator (64B aligned) ----
    char* p = (char*)d_ws;
    auto alloc = [&](size_t bytes) {
        char* r = p;
        p += (bytes + 63) & ~(size_t)63;
        return r;
    };
    float* outn = (float*)alloc(N_NODES * 4);
    float* inn  = (float*)alloc(N_NODES * 4);
    int* outc      = (int*)alloc(N_NODES * 4);
    int* inc       = (int*)alloc(N_NODES * 4);
    int* cursor    = (int*)alloc(N_NODES * 4);
    int* row_start = (int*)alloc((N_NODES + 1) * 4);
    int* bsum      = (int*)alloc(256 * 4);
    int* boff      = (int*)alloc(256 * 4);
    int* csr_src   = (int*)alloc(N_EDGES * 4);
    unsigned short* W0t = (unsigned short*)alloc(512 * 512 * 2);
    unsigned short* W1t = (unsigned short*)alloc(512 * 512 * 2);
    unsigned short* W2t = (unsigned short*)alloc(256 * 512 * 2);
    unsigned short* Af  = (unsigned short*)alloc((size_t)N_NODES * 512 * 2);
    unsigned short* H   = (unsigned short*)alloc((size_t)N_NODES * 512 * 2);

    const int NB = (N_NODES + 255) / 256;   // 196

    // ---- degrees + norms + CSR ----
    hipMemsetAsync(outc, 0, 3 * N_NODES * sizeof(int), stream);  // outc, inc, cursor contiguous
    hist_kernel<<<(N_EDGES + 255) / 256, 256, 0, stream>>>(src, dst, outc, inc);
    norm_kernel<<<(N_NODES + 255) / 256, 256, 0, stream>>>(outc, inc, outn, inn);
    scan1<<<NB, 256, 0, stream>>>(inc, row_start, bsum, N_NODES);
    scan2<<<1, 256, 0, stream>>>(bsum, boff, row_start, NB);
    scan3<<<NB, 256, 0, stream>>>(row_start, boff, N_NODES);
    fill_kernel<<<(N_EDGES + 255) / 256, 256, 0, stream>>>(src, dst, row_start, cursor, csr_src);

    // ---- weight transpose to fp16 ----
    conv_W<<<dim3(16, 16), 256, 0, stream>>>(W0, W0t, 512, 512);
    conv_W<<<dim3(16, 16), 256, 0, stream>>>(W1, W1t, 512, 512);
    conv_W<<<dim3(16, 8),  256, 0, stream>>>(W2, W2t, 512, 256);

    // ---- feature scale to fp16 ----
    long total4 = (long)N_NODES * 128;
    conv_A<<<(int)((total4 + 255) / 256), 256, 0, stream>>>(
        (const float4*)feat, outn, (ushort4*)Af, total4);

    dim3 g512((N_NODES + 127) / 128, 4);
    dim3 g256((N_NODES + 127) / 128, 2);
    const int NT = N_NODES / AGG_TILE;      // 3125 node tiles (exact)
    dim3 gAgg512(8, NT, 2);                 // 16 chunks: xcd = chunk%8, 2 phases
    dim3 gAgg256(8, NT, 1);                 // 8 chunks: one per XCD

    // ---- layer 0 ----
    gemm_mfma<<<g512, 256, 0, stream>>>(Af, W0t, H, N_NODES, 512);
    agg_f16_chunked<<<gAgg512, 256, 0, stream>>>(
        H, csr_src, row_start, inn, outn, b0, Af);

    // ---- layer 1 ----
    gemm_mfma<<<g512, 256, 0, stream>>>(Af, W1t, H, N_NODES, 512);
    agg_f16_chunked<<<gAgg512, 256, 0, stream>>>(
        H, csr_src, row_start, inn, outn, b1, Af);

    // ---- layer 2 (256 out, no relu, fp32) ----
    gemm_mfma<<<g256, 256, 0, stream>>>(Af, W2t, H, N_NODES, 256);
    agg_f32_chunked<<<gAgg256, 256, 0, stream>>>(
        H, csr_src, row_start, inn, b2, out);
}